// Round 1
// baseline (339.585 us; speedup 1.0000x reference)
//
#include <hip/hip_runtime.h>
#include <hip/hip_bf16.h>

typedef __attribute__((ext_vector_type(8))) short short8;
typedef __attribute__((ext_vector_type(4))) float floatx4;

#define DI __device__ __forceinline__

// Problem constants
constexpr int B_ = 2, N_ = 2048, H_ = 16, DK_ = 128, DV_ = 128, E_ = 2048;
constexpr int M_ = B_ * N_;          // 4096 token rows
constexpr int NCAT_ = 4 * E_;        // 8192 = q|k|v|g concat
constexpr int CH_ = 128;             // chunk length
constexpr int NC_ = N_ / CH_;        // 16 chunks
constexpr float KSCALE = 0.08838834764831845f; // 1/sqrt(128)

// Workspace layout (bytes)
constexpr long OFF_XB   = 0;                    // 16MB  bf16 x      (reused as RG after GEMM1)
constexpr long OFF_WCAT = 16777216;             // 32MB  bf16 Wq|Wk|Wv|Wg  (reused as MS f32 after GEMM1)
constexpr long OFF_WOB  = 50331648;             // 8MB   bf16 Wo
constexpr long OFF_BCAT = 58720256;             // 32KB  f32 concat bias
constexpr long OFF_Y    = 58753024;             // 64MB  bf16 [4096][8192] q|k|v|silu(g)
constexpr long OFF_KT   = 125861888;            // 16MB  bf16 Ktd [b][h][dk][t]  (k * dec^-(t%128))
constexpr long OFF_VT   = 142639104;            // 16MB  bf16 Vt  [b][h][dv][t]
constexpr long OFF_SCB  = 159416320;            // 16MB  bf16 per-chunk start states [bh][c][dv][dk]

DI unsigned short f2bf(float f){
  unsigned u = __float_as_uint(f);
  u += 0x7fffu + ((u >> 16) & 1u);
  return (unsigned short)(u >> 16);
}
DI float bf2f(unsigned short s){ return __uint_as_float(((unsigned)s) << 16); }

DI void gload_lds16(const void* g, void* l){
  __builtin_amdgcn_global_load_lds(
      (const __attribute__((address_space(1))) unsigned int*)g,
      (__attribute__((address_space(3))) unsigned int*)l, 16, 0, 0);
}

// ---------------- prep: f32 -> bf16 cast ----------------
__global__ void k_cast(const float* __restrict__ s, unsigned short* __restrict__ d, int n){
  long i = ((long)blockIdx.x * blockDim.x + threadIdx.x) * 8;
  if(i >= n) return;
  float4 v0 = *(const float4*)(s + i);
  float4 v1 = *(const float4*)(s + i + 4);
  short8 o;
  o[0]=(short)f2bf(v0.x); o[1]=(short)f2bf(v0.y); o[2]=(short)f2bf(v0.z); o[3]=(short)f2bf(v0.w);
  o[4]=(short)f2bf(v1.x); o[5]=(short)f2bf(v1.y); o[6]=(short)f2bf(v1.z); o[7]=(short)f2bf(v1.w);
  *(short8*)(d + i) = o;
}

__global__ void k_bcat(const float* __restrict__ bq, const float* __restrict__ bk,
                       const float* __restrict__ bv, const float* __restrict__ bg,
                       float* __restrict__ bcat){
  int i = blockIdx.x * blockDim.x + threadIdx.x;
  float v;
  if(i < 2048)      v = bq[i];
  else if(i < 4096) v = bk[i - 2048];
  else if(i < 6144) v = bv[i - 4096];
  else              v = bg[i - 6144];
  bcat[i] = v;
}

// ---------------- GEMM: C[M][Ncols] = A[M][K] @ Bt[Ncols][K]^T ----------------
// EPI 0: bf16 out, bias + k-scale + silu(g) per column section (QKVG)
// EPI 1: f32 out + bias (final output)
template<int EPI>
__global__ __launch_bounds__(256)
void k_gemm(const unsigned short* __restrict__ A,
            const unsigned short* __restrict__ Bt,
            void* __restrict__ outp,
            const float* __restrict__ bias,
            int M, int Ncols, int K, int NB)
{
  __shared__ unsigned short lA[128*64];
  __shared__ unsigned short lB[128*64];
  const int bid = blockIdx.x;
  const int bm = bid / NB, bn = bid % NB;
  const int tid = threadIdx.x;
  const int wave = tid >> 6, lane = tid & 63;
  const int wr = wave >> 1, wc = wave & 1;

  floatx4 acc[4][4] = {};

  int srow[4], scol[4];
  #pragma unroll
  for(int is=0; is<4; ++is){
    int o = is*4096 + wave*1024 + lane*16;     // byte offset in 16KB tile
    int row = o >> 7;
    int logcb = (o & 127) ^ ((row & 7) << 4);  // inverse-swizzled source column
    srow[is] = row; scol[is] = logcb >> 1;
  }
  const unsigned short* Abase = A + (long)bm * 128 * K;
  const unsigned short* Bbase = Bt + (long)bn * 128 * K;

  const int nkt = K >> 6;
  for(int kt=0; kt<nkt; ++kt){
    const int k0 = kt << 6;
    #pragma unroll
    for(int is=0; is<4; ++is){
      gload_lds16(Abase + (long)srow[is]*K + k0 + scol[is], &lA[(is*4096 + wave*1024) >> 1]);
      gload_lds16(Bbase + (long)srow[is]*K + k0 + scol[is], &lB[(is*4096 + wave*1024) >> 1]);
    }
    __syncthreads();
    #pragma unroll
    for(int kk=0; kk<2; ++kk){
      const int cb = (kk<<6) + ((lane>>4)<<4);
      short8 af[4], bfr[4];
      #pragma unroll
      for(int i=0;i<4;++i){
        int row = (wr<<6) + (i<<4) + (lane&15);
        af[i] = *(const short8*)((const char*)lA + (row<<7) + (cb ^ ((row&7)<<4)));
      }
      #pragma unroll
      for(int j=0;j<4;++j){
        int row = (wc<<6) + (j<<4) + (lane&15);
        bfr[j] = *(const short8*)((const char*)lB + (row<<7) + (cb ^ ((row&7)<<4)));
      }
      #pragma unroll
      for(int i=0;i<4;++i)
        #pragma unroll
        for(int j=0;j<4;++j)
          acc[i][j] = __builtin_amdgcn_mfma_f32_16x16x32_bf16(af[i], bfr[j], acc[i][j], 0,0,0);
    }
    __syncthreads();
  }

  #pragma unroll
  for(int i=0;i<4;++i){
    #pragma unroll
    for(int j=0;j<4;++j){
      #pragma unroll
      for(int r=0;r<4;++r){
        int row = bm*128 + (wr<<6) + (i<<4) + ((lane>>4)<<2) + r;
        int col = bn*128 + (wc<<6) + (j<<4) + (lane&15);
        float v = acc[i][j][r] + bias[col];
        if(EPI == 0){
          int sec = col >> 11;
          if(sec == 1) v *= KSCALE;
          else if(sec == 3) v = v / (1.f + __expf(-v));   // silu
          ((unsigned short*)outp)[(long)row * Ncols + col] = f2bf(v);
        } else {
          ((float*)outp)[(long)row * Ncols + col] = v;
        }
      }
    }
  }
}

// ---------------- transpose K,V to t-contiguous; bake dec^-(t%128) into K ----------------
__global__ __launch_bounds__(256)
void k_transpose(const unsigned short* __restrict__ Y,
                 unsigned short* __restrict__ Kt, unsigned short* __restrict__ Vt){
  __shared__ unsigned short lt[128][136];
  int bid = blockIdx.x;
  int op = bid >> 9;            // 0: K, 1: V
  int r  = bid & 511;
  int bh = r >> 4, c = r & 15, b = bh >> 4, h = bh & 15;
  int tid = threadIdx.x;
  float dec = 1.f - exp2f(-5.f - (float)h);
  float l2d = log2f(dec);
  int sec = op ? 4096 : 2048;
  unsigned short* Dst = op ? Vt : Kt;

  #pragma unroll
  for(int p=0;p<8;++p){
    int t = p*16 + (tid>>4);
    long src = ((long)(b*N_ + c*CH_ + t)) * NCAT_ + sec + h*128 + (tid&15)*8;
    short8 v = *(const short8*)(Y + src);
    if(op == 0){
      float f = exp2f(-(float)t * l2d);   // dec^{-t}
      #pragma unroll
      for(int u=0;u<8;++u) v[u] = (short)f2bf(bf2f((unsigned short)v[u]) * f);
    }
    *(short8*)&lt[t][(tid&15)*8] = v;
  }
  __syncthreads();
  #pragma unroll
  for(int p=0;p<8;++p){
    int dk = p*16 + (tid>>4);
    int tc = (tid&15)*8;
    short8 o;
    #pragma unroll
    for(int u=0;u<8;++u) o[u] = (short)lt[tc+u][dk];
    *(short8*)(Dst + ((long)(bh*128 + dk)) * N_ + c*CH_ + tc) = o;
  }
}

// ---------------- per-chunk summary Mt_c[dv][dk] = dec^{C-1} * sum_t Vt[dv][t]*Ktd[dk][t] ----------------
__global__ __launch_bounds__(256)
void k_chunksum(const unsigned short* __restrict__ Ktd, const unsigned short* __restrict__ Vt,
                float* __restrict__ MS){
  int bid = blockIdx.x;            // 512: bh*16 + c
  int bh = bid >> 4, c = bid & 15, h = bh & 15;
  int tid = threadIdx.x, wave = tid >> 6, lane = tid & 63;
  int wr = wave >> 1, wc = wave & 1;
  floatx4 acc[4][4] = {};
  const unsigned short* Vb = Vt  + (long)bh*128*N_ + c*CH_;
  const unsigned short* Kb = Ktd + (long)bh*128*N_ + c*CH_;

  #pragma unroll
  for(int kk=0;kk<4;++kk){
    int tl = kk*32 + ((lane>>4)<<3);
    short8 af[4], bfr[4];
    #pragma unroll
    for(int i=0;i<4;++i){ int dv = (wr<<6)+(i<<4)+(lane&15); af[i]  = *(const short8*)(Vb + (long)dv*N_ + tl); }
    #pragma unroll
    for(int j=0;j<4;++j){ int dk = (wc<<6)+(j<<4)+(lane&15); bfr[j] = *(const short8*)(Kb + (long)dk*N_ + tl); }
    #pragma unroll
    for(int i=0;i<4;++i)
      #pragma unroll
      for(int j=0;j<4;++j)
        acc[i][j] = __builtin_amdgcn_mfma_f32_16x16x32_bf16(af[i], bfr[j], acc[i][j], 0,0,0);
  }
  float dec = 1.f - exp2f(-5.f - (float)h);
  float scale = exp2f(127.f * log2f(dec));    // dec^{C-1}
  float* Mo = MS + ((long)bh*NC_ + c) * 16384;
  #pragma unroll
  for(int i=0;i<4;++i)
    #pragma unroll
    for(int j=0;j<4;++j)
      #pragma unroll
      for(int r=0;r<4;++r){
        int dv = (wr<<6)+(i<<4)+((lane>>4)<<2)+r;
        int dk = (wc<<6)+(j<<4)+(lane&15);
        Mo[dv*128 + dk] = acc[i][j][r] * scale;
      }
}

// ---------------- sequential scan over chunks; emit per-chunk start states (bf16) + final state ----------------
__global__ __launch_bounds__(256)
void k_scan(const float* __restrict__ MS, unsigned short* __restrict__ Scb,
            float* __restrict__ stateOut){
  int bh = blockIdx.x, tid = threadIdx.x, h = bh & 15;
  float dec = 1.f - exp2f(-5.f - (float)h);
  float decC = exp2f(128.f * log2f(dec));     // dec^C
  floatx4 S[16] = {};
  const float* base = MS + (long)bh * NC_ * 16384;
  unsigned short* sb = Scb + (long)bh * NC_ * 16384;
  for(int c=0;c<NC_;++c){
    const float* p = base + c*16384;
    unsigned short* q = sb + c*16384;
    #pragma unroll
    for(int g=0;g<16;++g){
      int idx = (g*256 + tid)*4;
      floatx4 m = *(const floatx4*)(p + idx);
      #pragma unroll
      for(int u=0;u<4;++u) q[idx+u] = f2bf(S[g][u]);
      S[g] = decC * S[g] + m;
    }
  }
  // final state: element e = dv*128+dk (transposed layout) -> out [b][h][dk][dv]
  #pragma unroll
  for(int g=0;g<16;++g){
    int idx = (g*256 + tid)*4;
    #pragma unroll
    for(int u=0;u<4;++u){
      int e = idx + u, dv = e >> 7, dk = e & 127;
      stateOut[(long)bh*16384 + dk*128 + dv] = S[g][u];
    }
  }
}

// ---------------- retention output: masked decayed QK^T @ V + cross, group-norm, gate ----------------
__global__ __launch_bounds__(256)
void k_ret(const unsigned short* __restrict__ Y, const unsigned short* __restrict__ Vt,
           const unsigned short* __restrict__ Scb, unsigned short* __restrict__ RG){
  __shared__ unsigned short sQ[128*128];   // Qd = q * dec^t   (swizzled)
  __shared__ unsigned short sK[128*128];   // Kd = k * dec^-s ; reused for P
  int bid = blockIdx.x;
  int bh = bid >> 4, c = bid & 15, b = bh >> 4, h = bh & 15;
  int tid = threadIdx.x, w = tid >> 6, lane = tid & 63;
  float dec = 1.f - exp2f(-5.f - (float)h);
  float l2d = log2f(dec);

  #pragma unroll
  for(int p=0;p<8;++p){
    int t = p*16 + (tid>>4);
    long row = (long)(b*N_ + c*CH_ + t) * NCAT_ + h*128 + (tid&15)*8;
    short8 qv = *(const short8*)(Y + row);          // q section
    short8 kv = *(const short8*)(Y + row + 2048);   // k section
    float fq = exp2f((float)t * l2d);
    float fk = exp2f(-(float)t * l2d);
    short8 qs, ks;
    #pragma unroll
    for(int u=0;u<8;++u){
      qs[u] = (short)f2bf(bf2f((unsigned short)qv[u]) * fq);
      ks[u] = (short)f2bf(bf2f((unsigned short)kv[u]) * fk);
    }
    int ad = t*256 + (((tid&15)*16) ^ ((t&7)<<4));
    *(short8*)((char*)sQ + ad) = qs;
    *(short8*)((char*)sK + ad) = ks;
  }
  __syncthreads();

  floatx4 acc[2][8] = {};
  // QK^T (already includes dec^{t-s})
  #pragma unroll
  for(int kk=0;kk<4;++kk){
    int cb = (kk<<6) + ((lane>>4)<<4);
    short8 af[2], bfr[8];
    #pragma unroll
    for(int i=0;i<2;++i){ int t = w*32 + (i<<4) + (lane&15); af[i] = *(const short8*)((const char*)sQ + t*256 + (cb ^ ((t&7)<<4))); }
    #pragma unroll
    for(int j=0;j<8;++j){ int s = (j<<4) + (lane&15); bfr[j] = *(const short8*)((const char*)sK + s*256 + (cb ^ ((s&7)<<4))); }
    #pragma unroll
    for(int i=0;i<2;++i)
      #pragma unroll
      for(int j=0;j<8;++j)
        acc[i][j] = __builtin_amdgcn_mfma_f32_16x16x32_bf16(af[i], bfr[j], acc[i][j], 0,0,0);
  }
  __syncthreads();   // all waves done reading sK

  // causal mask, write P (bf16) into sK
  #pragma unroll
  for(int i=0;i<2;++i)
    #pragma unroll
    for(int j=0;j<8;++j)
      #pragma unroll
      for(int r=0;r<4;++r){
        int t = w*32 + (i<<4) + ((lane>>4)<<2) + r;
        int s = (j<<4) + (lane&15);
        float v = (s <= t) ? acc[i][j][r] : 0.f;
        *(unsigned short*)((char*)sK + t*256 + ((s*2) ^ ((t&7)<<4))) = f2bf(v);
      }
  __syncthreads();

  #pragma unroll
  for(int i=0;i<2;++i)
    #pragma unroll
    for(int j=0;j<8;++j)
      #pragma unroll
      for(int u=0;u<4;++u) acc[i][j][u] = 0.f;

  // ret = P @ V
  const unsigned short* Vb = Vt + (long)bh*128*N_ + c*CH_;
  #pragma unroll
  for(int kk=0;kk<4;++kk){
    int cb = (kk<<6) + ((lane>>4)<<4);
    int sg = kk*32 + ((lane>>4)<<3);
    short8 af[2], bfr[8];
    #pragma unroll
    for(int i=0;i<2;++i){ int t = w*32 + (i<<4) + (lane&15); af[i] = *(const short8*)((const char*)sK + t*256 + (cb ^ ((t&7)<<4))); }
    #pragma unroll
    for(int j=0;j<8;++j){ int dv = (j<<4) + (lane&15); bfr[j] = *(const short8*)(Vb + (long)dv*N_ + sg); }
    #pragma unroll
    for(int i=0;i<2;++i)
      #pragma unroll
      for(int j=0;j<8;++j)
        acc[i][j] = __builtin_amdgcn_mfma_f32_16x16x32_bf16(af[i], bfr[j], acc[i][j], 0,0,0);
  }
  // + dec^{t+1} * q @ S_c   (A = Qd*dec, B = Scb[dv][dk])
  const unsigned short* Sb = Scb + ((long)bh*NC_ + c) * 16384;
  #pragma unroll
  for(int kk=0;kk<4;++kk){
    int cb = (kk<<6) + ((lane>>4)<<4);
    int kg = kk*32 + ((lane>>4)<<3);
    short8 af[2], bfr[8];
    #pragma unroll
    for(int i=0;i<2;++i){
      int t = w*32 + (i<<4) + (lane&15);
      short8 qv = *(const short8*)((const char*)sQ + t*256 + (cb ^ ((t&7)<<4)));
      #pragma unroll
      for(int u=0;u<8;++u) af[i][u] = (short)f2bf(bf2f((unsigned short)qv[u]) * dec);
    }
    #pragma unroll
    for(int j=0;j<8;++j){ int dv = (j<<4) + (lane&15); bfr[j] = *(const short8*)(Sb + (long)dv*128 + kg); }
    #pragma unroll
    for(int i=0;i<2;++i)
      #pragma unroll
      for(int j=0;j<8;++j)
        acc[i][j] = __builtin_amdgcn_mfma_f32_16x16x32_bf16(af[i], bfr[j], acc[i][j], 0,0,0);
  }

  // group-norm over DV per row, gate, write bf16
  #pragma unroll
  for(int i=0;i<2;++i){
    #pragma unroll
    for(int r=0;r<4;++r){
      float s1 = 0.f, s2 = 0.f;
      #pragma unroll
      for(int j=0;j<8;++j){ float v = acc[i][j][r]; s1 += v; s2 += v*v; }
      #pragma unroll
      for(int off=1; off<16; off<<=1){ s1 += __shfl_xor(s1, off); s2 += __shfl_xor(s2, off); }
      float mu  = s1 * (1.f/128.f);
      float var = s2 * (1.f/128.f) - mu*mu;
      float inv = rsqrtf(var + 1e-6f);
      int t = w*32 + (i<<4) + ((lane>>4)<<2) + r;
      long mrow = (long)(b*N_ + c*CH_ + t);
      #pragma unroll
      for(int j=0;j<8;++j){
        int dv = (j<<4) + (lane&15);
        float v = (acc[i][j][r] - mu) * inv;
        float g = bf2f(Y[mrow*NCAT_ + 6144 + h*128 + dv]);
        RG[mrow*E_ + h*128 + dv] = f2bf(v * g);
      }
    }
  }
}

// ---------------- launch ----------------
extern "C" void kernel_launch(void* const* d_in, const int* in_sizes, int n_in,
                              void* d_out, int out_size, void* d_ws, size_t ws_size,
                              hipStream_t stream) {
  const float* x  = (const float*)d_in[0];
  const float* Wq = (const float*)d_in[1];
  const float* bq = (const float*)d_in[2];
  const float* Wk = (const float*)d_in[3];
  const float* bk = (const float*)d_in[4];
  const float* Wv = (const float*)d_in[5];
  const float* bv = (const float*)d_in[6];
  const float* Wg = (const float*)d_in[7];
  const float* bg = (const float*)d_in[8];
  const float* Wo = (const float*)d_in[9];
  const float* bo = (const float*)d_in[10];

  char* ws = (char*)d_ws;
  unsigned short* xb   = (unsigned short*)(ws + OFF_XB);
  unsigned short* Wcat = (unsigned short*)(ws + OFF_WCAT);
  unsigned short* Wob  = (unsigned short*)(ws + OFF_WOB);
  float*          bcat = (float*)(ws + OFF_BCAT);
  unsigned short* Y    = (unsigned short*)(ws + OFF_Y);
  unsigned short* Ktd  = (unsigned short*)(ws + OFF_KT);
  unsigned short* Vt   = (unsigned short*)(ws + OFF_VT);
  unsigned short* Scb  = (unsigned short*)(ws + OFF_SCB);
  float*          MS   = (float*)(ws + OFF_WCAT);   // reuse after GEMM1
  unsigned short* RG   = (unsigned short*)(ws + OFF_XB); // reuse after GEMM1

  float* outp     = (float*)d_out;
  float* stateOut = outp + (long)M_ * E_;   // 8,388,608

  // prep
  k_cast<<<4096, 256, 0, stream>>>(x, xb, M_*E_);
  k_cast<<<2048, 256, 0, stream>>>(Wq, Wcat + 0L,        E_*E_);
  k_cast<<<2048, 256, 0, stream>>>(Wk, Wcat + 1L*E_*E_,  E_*E_);
  k_cast<<<2048, 256, 0, stream>>>(Wv, Wcat + 2L*E_*E_,  E_*E_);
  k_cast<<<2048, 256, 0, stream>>>(Wg, Wcat + 3L*E_*E_,  E_*E_);
  k_cast<<<2048, 256, 0, stream>>>(Wo, Wob, E_*E_);
  k_bcat<<<32, 256, 0, stream>>>(bq, bk, bv, bg, bcat);

  // fused QKVG projection
  k_gemm<0><<<(M_/128)*(NCAT_/128), 256, 0, stream>>>(xb, Wcat, Y, bcat, M_, NCAT_, E_, NCAT_/128);

  // t-contiguous K (decay-weighted) and V
  k_transpose<<<1024, 256, 0, stream>>>(Y, Ktd, Vt);

  // retention
  k_chunksum<<<512, 256, 0, stream>>>(Ktd, Vt, MS);
  k_scan<<<32, 256, 0, stream>>>(MS, Scb, stateOut);
  k_ret<<<512, 256, 0, stream>>>(Y, Vt, Scb, RG);

  // output projection
  k_gemm<1><<<(M_/128)*(E_/128), 256, 0, stream>>>(RG, Wob, (void*)outp, bo, M_, E_, E_, E_/128);
}

// Round 2
// 300.372 us; speedup vs baseline: 1.1305x; 1.1305x over previous
//
#include <hip/hip_runtime.h>
#include <hip/hip_bf16.h>

typedef __attribute__((ext_vector_type(8))) short short8;
typedef __attribute__((ext_vector_type(4))) short short4v;
typedef __attribute__((ext_vector_type(4))) float floatx4;

#define DI __device__ __forceinline__

// Problem constants
constexpr int B_ = 2, N_ = 2048, H_ = 16, DK_ = 128, DV_ = 128, E_ = 2048;
constexpr int M_ = B_ * N_;          // 4096 token rows
constexpr int NCAT_ = 4 * E_;        // 8192 = q|k|v|g concat
constexpr int CH_ = 128;             // chunk length
constexpr int NC_ = N_ / CH_;        // 16 chunks
constexpr float KSCALE = 0.08838834764831845f; // 1/sqrt(128)

// Workspace layout (bytes)
constexpr long OFF_XB   = 0;                    // 16MB  bf16 x      (reused as RG after GEMM1)
constexpr long OFF_WCAT = 16777216;             // 32MB  bf16 Wq|Wk|Wv|Wg  (reused as MS f32 after GEMM1)
constexpr long OFF_WOB  = 50331648;             // 8MB   bf16 Wo
constexpr long OFF_BCAT = 58720256;             // 32KB  f32 concat bias
constexpr long OFF_Y    = 58753024;             // 64MB  bf16 [4096][8192] q|k|v|silu(g)
constexpr long OFF_KT   = 125861888;            // 16MB  bf16 Ktd [b][h][dk][t]  (k * dec^-(t%128))
constexpr long OFF_VT   = 142639104;            // 16MB  bf16 Vt  [b][h][dv][t]
constexpr long OFF_SCB  = 159416320;            // 16MB  bf16 per-chunk start states [bh][c][dv][dk]

DI unsigned short f2bf(float f){
  unsigned u = __float_as_uint(f);
  u += 0x7fffu + ((u >> 16) & 1u);
  return (unsigned short)(u >> 16);
}
DI float bf2f(unsigned short s){ return __uint_as_float(((unsigned)s) << 16); }

DI void gload_lds16(const void* g, void* l){
  __builtin_amdgcn_global_load_lds(
      (const __attribute__((address_space(1))) unsigned int*)g,
      (__attribute__((address_space(3))) unsigned int*)l, 16, 0, 0);
}

// ---------------- prep: f32 -> bf16 cast ----------------
__global__ void k_cast(const float* __restrict__ s, unsigned short* __restrict__ d, int n){
  long i = ((long)blockIdx.x * blockDim.x + threadIdx.x) * 8;
  if(i >= n) return;
  float4 v0 = *(const float4*)(s + i);
  float4 v1 = *(const float4*)(s + i + 4);
  short8 o;
  o[0]=(short)f2bf(v0.x); o[1]=(short)f2bf(v0.y); o[2]=(short)f2bf(v0.z); o[3]=(short)f2bf(v0.w);
  o[4]=(short)f2bf(v1.x); o[5]=(short)f2bf(v1.y); o[6]=(short)f2bf(v1.z); o[7]=(short)f2bf(v1.w);
  *(short8*)(d + i) = o;
}

__global__ void k_bcat(const float* __restrict__ bq, const float* __restrict__ bk,
                       const float* __restrict__ bv, const float* __restrict__ bg,
                       float* __restrict__ bcat){
  int i = blockIdx.x * blockDim.x + threadIdx.x;
  float v;
  if(i < 2048)      v = bq[i];
  else if(i < 4096) v = bk[i - 2048];
  else if(i < 6144) v = bv[i - 4096];
  else              v = bg[i - 6144];
  bcat[i] = v;
}

// ================= 256x256 8-phase GEMM (QKVG projection) =================
// A[4096][2048] bf16, Bt[8192][2048] bf16 -> Y[4096][8192] bf16 (bias + section epilogue)
// 512 threads = 8 waves (2M x 4N), per-wave C = 128x64, BK=64, LDS 128KB dbuf, XOR swizzle.
__global__ __launch_bounds__(512, 2)
void k_gemm256(const unsigned short* __restrict__ A,
               const unsigned short* __restrict__ Bt,
               unsigned short* __restrict__ Y,
               const float* __restrict__ bias)
{
  extern __shared__ unsigned short lds[];   // [2 buf][A 16384][B 16384] -> A at buf*16384, B at 32768+buf*16384
  constexpr int K = 2048;
  constexpr int NKT = K / 64;

  const int tid = threadIdx.x;
  const int wave = tid >> 6, lane = tid & 63;
  const int wr = wave >> 2, wc = wave & 3;

  // XCD-bijective 8x8 supertile swizzle: xcd g = bid%8 owns one 8x8 (bm,bn) supertile
  int bid = blockIdx.x;
  int g = bid & 7, w = bid >> 3;            // w in 0..63
  int bm = (g & 1) * 8 + (w & 7);           // 0..15
  int bn = (g >> 1) * 8 + (w >> 3);         // 0..31

  const unsigned short* Ab = A  + (long)bm * 256 * K;
  const unsigned short* Bb = Bt + (long)bn * 256 * K;

  // staging per-lane geometry (linear LDS dest, inverse-swizzled global source)
  const int rowbase = wave * 8 + (lane >> 3);                 // 0..63
  const int ce      = ((lane & 7) ^ (lane >> 3)) * 8;         // element col of 16B chunk
  const unsigned short* Aln = Ab + (long)rowbase * K + ce;
  const unsigned short* Bln = Bb + (long)rowbase * K + ce;

  // ds_read per-lane geometry
  const int l15 = lane & 15;
  const int cx0 = ((lane >> 4) ^ (lane & 7)) << 4;            // byte col (k=0); k=1 -> ^0x40
  // A row byte-bases (per quarter q, rep i): (wr*128 + q*64 + i*16 + l15)*128
  int arow[4], brow[4];
  #pragma unroll
  for(int i=0;i<4;++i) arow[i] = (wr*128 + i*16 + l15) << 7;
  #pragma unroll
  for(int j=0;j<4;++j) brow[j] = (wc*64 + j*16 + l15) << 7;

  floatx4 acc[8][4] = {};
  short8 a[4][2], b0[2][2], b1[2][2];

#define STAGE(kt, buf) do{                                                        \
    const long _ko = (long)(kt) * 64;                                             \
    _Pragma("unroll")                                                             \
    for(int s=0;s<4;++s)                                                          \
      gload_lds16(Aln + (long)s*64*K + _ko, &lds[(buf)*16384 + s*4096 + wave*512]); \
    _Pragma("unroll")                                                             \
    for(int s=0;s<4;++s)                                                          \
      gload_lds16(Bln + (long)s*64*K + _ko, &lds[32768 + (buf)*16384 + s*4096 + wave*512]); \
  }while(0)

  // prologue: tile 0 -> buf 0
  STAGE(0, 0);
  asm volatile("s_waitcnt vmcnt(0)" ::: "memory");
  __builtin_amdgcn_s_barrier();

  for(int u=0; u<NKT; ++u){
    const int cur = u & 1;
    const char* cA = (const char*)lds + cur*32768;
    const char* cB = (const char*)lds + 65536 + cur*32768;

    // ---- P0: stage next tile; ds_read quadrant (M0, N0); MFMA ----
    STAGE((u+1)&(NKT-1), cur^1);
    #pragma unroll
    for(int i=0;i<4;++i)
      #pragma unroll
      for(int k=0;k<2;++k)
        a[i][k] = *(const short8*)(cA + arow[i] + (cx0 ^ (k<<6)));
    #pragma unroll
    for(int j=0;j<2;++j)
      #pragma unroll
      for(int k=0;k<2;++k)
        b0[j][k] = *(const short8*)(cB + brow[j] + (cx0 ^ (k<<6)));
    __builtin_amdgcn_s_barrier();
    __builtin_amdgcn_s_setprio(1);
    #pragma unroll
    for(int i=0;i<4;++i)
      #pragma unroll
      for(int j=0;j<2;++j)
        #pragma unroll
        for(int k=0;k<2;++k)
          acc[i][j] = __builtin_amdgcn_mfma_f32_16x16x32_bf16(a[i][k], b0[j][k], acc[i][j], 0,0,0);
    __builtin_amdgcn_s_setprio(0);
    __builtin_amdgcn_s_barrier();

    // ---- P1: ds_read B N1; MFMA quadrant (M0, N1) ----
    #pragma unroll
    for(int j=0;j<2;++j)
      #pragma unroll
      for(int k=0;k<2;++k)
        b1[j][k] = *(const short8*)(cB + brow[2+j] + (cx0 ^ (k<<6)));
    __builtin_amdgcn_s_barrier();
    __builtin_amdgcn_s_setprio(1);
    #pragma unroll
    for(int i=0;i<4;++i)
      #pragma unroll
      for(int j=0;j<2;++j)
        #pragma unroll
        for(int k=0;k<2;++k)
          acc[i][2+j] = __builtin_amdgcn_mfma_f32_16x16x32_bf16(a[i][k], b1[j][k], acc[i][2+j], 0,0,0);
    __builtin_amdgcn_s_setprio(0);
    __builtin_amdgcn_s_barrier();

    // ---- P2: ds_read A M1 (overwrite a); MFMA quadrant (M1, N1) ----
    #pragma unroll
    for(int i=0;i<4;++i)
      #pragma unroll
      for(int k=0;k<2;++k)
        a[i][k] = *(const short8*)(cA + arow[i] + 8192 + (cx0 ^ (k<<6)));
    __builtin_amdgcn_s_barrier();
    __builtin_amdgcn_s_setprio(1);
    #pragma unroll
    for(int i=0;i<4;++i)
      #pragma unroll
      for(int j=0;j<2;++j)
        #pragma unroll
        for(int k=0;k<2;++k)
          acc[4+i][2+j] = __builtin_amdgcn_mfma_f32_16x16x32_bf16(a[i][k], b1[j][k], acc[4+i][2+j], 0,0,0);
    __builtin_amdgcn_s_setprio(0);
    __builtin_amdgcn_s_barrier();

    // ---- P3: MFMA quadrant (M1, N0); tile-boundary drain ----
    __builtin_amdgcn_s_setprio(1);
    #pragma unroll
    for(int i=0;i<4;++i)
      #pragma unroll
      for(int j=0;j<2;++j)
        #pragma unroll
        for(int k=0;k<2;++k)
          acc[4+i][j] = __builtin_amdgcn_mfma_f32_16x16x32_bf16(a[i][k], b0[j][k], acc[4+i][j], 0,0,0);
    __builtin_amdgcn_s_setprio(0);
    asm volatile("s_waitcnt vmcnt(0)" ::: "memory");
    __builtin_amdgcn_s_barrier();
  }
#undef STAGE

  // epilogue: bias + section transforms, bf16 store
  #pragma unroll
  for(int i=0;i<8;++i){
    const int rowi = bm*256 + wr*128 + (i>>2)*64 + (i&3)*16 + ((lane>>4)<<2);
    #pragma unroll
    for(int j=0;j<4;++j){
      const int col = bn*256 + wc*64 + j*16 + (lane&15);
      const float bs = bias[col];
      const int sec = col >> 11;
      #pragma unroll
      for(int r=0;r<4;++r){
        float v = acc[i][j][r] + bs;
        if(sec == 1) v *= KSCALE;
        else if(sec == 3) v = v / (1.f + __expf(-v));   // silu
        Y[(long)(rowi + r) * NCAT_ + col] = f2bf(v);
      }
    }
  }
}

// ---------------- 128^2 GEMM (kept for output projection) ----------------
template<int EPI>
__global__ __launch_bounds__(256)
void k_gemm(const unsigned short* __restrict__ A,
            const unsigned short* __restrict__ Bt,
            void* __restrict__ outp,
            const float* __restrict__ bias,
            int M, int Ncols, int K, int NB)
{
  __shared__ unsigned short lA[128*64];
  __shared__ unsigned short lB[128*64];
  const int bid = blockIdx.x;
  const int bm = bid / NB, bn = bid % NB;
  const int tid = threadIdx.x;
  const int wave = tid >> 6, lane = tid & 63;
  const int wr = wave >> 1, wc = wave & 1;

  floatx4 acc[4][4] = {};

  int srow[4], scol[4];
  #pragma unroll
  for(int is=0; is<4; ++is){
    int o = is*4096 + wave*1024 + lane*16;     // byte offset in 16KB tile
    int row = o >> 7;
    int logcb = (o & 127) ^ ((row & 7) << 4);  // inverse-swizzled source column
    srow[is] = row; scol[is] = logcb >> 1;
  }
  const unsigned short* Abase = A + (long)bm * 128 * K;
  const unsigned short* Bbase = Bt + (long)bn * 128 * K;

  const int nkt = K >> 6;
  for(int kt=0; kt<nkt; ++kt){
    const int k0 = kt << 6;
    #pragma unroll
    for(int is=0; is<4; ++is){
      gload_lds16(Abase + (long)srow[is]*K + k0 + scol[is], &lA[(is*4096 + wave*1024) >> 1]);
      gload_lds16(Bbase + (long)srow[is]*K + k0 + scol[is], &lB[(is*4096 + wave*1024) >> 1]);
    }
    __syncthreads();
    #pragma unroll
    for(int kk=0; kk<2; ++kk){
      const int cb = (kk<<6) + ((lane>>4)<<4);
      short8 af[4], bfr[4];
      #pragma unroll
      for(int i=0;i<4;++i){
        int row = (wr<<6) + (i<<4) + (lane&15);
        af[i] = *(const short8*)((const char*)lA + (row<<7) + (cb ^ ((row&7)<<4)));
      }
      #pragma unroll
      for(int j=0;j<4;++j){
        int row = (wc<<6) + (j<<4) + (lane&15);
        bfr[j] = *(const short8*)((const char*)lB + (row<<7) + (cb ^ ((row&7)<<4)));
      }
      #pragma unroll
      for(int i=0;i<4;++i)
        #pragma unroll
        for(int j=0;j<4;++j)
          acc[i][j] = __builtin_amdgcn_mfma_f32_16x16x32_bf16(af[i], bfr[j], acc[i][j], 0,0,0);
    }
    __syncthreads();
  }

  #pragma unroll
  for(int i=0;i<4;++i){
    #pragma unroll
    for(int j=0;j<4;++j){
      #pragma unroll
      for(int r=0;r<4;++r){
        int row = bm*128 + (wr<<6) + (i<<4) + ((lane>>4)<<2) + r;
        int col = bn*128 + (wc<<6) + (j<<4) + (lane&15);
        float v = acc[i][j][r] + bias[col];
        if(EPI == 0){
          int sec = col >> 11;
          if(sec == 1) v *= KSCALE;
          else if(sec == 3) v = v / (1.f + __expf(-v));   // silu
          ((unsigned short*)outp)[(long)row * Ncols + col] = f2bf(v);
        } else {
          ((float*)outp)[(long)row * Ncols + col] = v;
        }
      }
    }
  }
}

// ---------------- transpose K,V to t-contiguous; bake dec^-(t%128) into K ----------------
__global__ __launch_bounds__(256)
void k_transpose(const unsigned short* __restrict__ Y,
                 unsigned short* __restrict__ Kt, unsigned short* __restrict__ Vt){
  __shared__ unsigned short lt[128][136];
  int bid = blockIdx.x;
  int op = bid >> 9;            // 0: K, 1: V
  int r  = bid & 511;
  int bh = r >> 4, c = r & 15, b = bh >> 4, h = bh & 15;
  int tid = threadIdx.x;
  float dec = 1.f - exp2f(-5.f - (float)h);
  float l2d = log2f(dec);
  int sec = op ? 4096 : 2048;
  unsigned short* Dst = op ? Vt : Kt;

  #pragma unroll
  for(int p=0;p<8;++p){
    int t = p*16 + (tid>>4);
    long src = ((long)(b*N_ + c*CH_ + t)) * NCAT_ + sec + h*128 + (tid&15)*8;
    short8 v = *(const short8*)(Y + src);
    if(op == 0){
      float f = exp2f(-(float)t * l2d);   // dec^{-t}
      #pragma unroll
      for(int u=0;u<8;++u) v[u] = (short)f2bf(bf2f((unsigned short)v[u]) * f);
    }
    *(short8*)&lt[t][(tid&15)*8] = v;
  }
  __syncthreads();
  #pragma unroll
  for(int p=0;p<8;++p){
    int dk = p*16 + (tid>>4);
    int tc = (tid&15)*8;
    short8 o;
    #pragma unroll
    for(int u=0;u<8;++u) o[u] = (short)lt[tc+u][dk];
    *(short8*)(Dst + ((long)(bh*128 + dk)) * N_ + c*CH_ + tc) = o;
  }
}

// ---------------- per-chunk summary Mt_c[dv][dk] = dec^{C-1} * sum_t Vt[dv][t]*Ktd[dk][t] ----------------
__global__ __launch_bounds__(256)
void k_chunksum(const unsigned short* __restrict__ Ktd, const unsigned short* __restrict__ Vt,
                float* __restrict__ MS){
  int bid = blockIdx.x;            // 512: bh*16 + c
  int bh = bid >> 4, c = bid & 15, h = bh & 15;
  int tid = threadIdx.x, wave = tid >> 6, lane = tid & 63;
  int wr = wave >> 1, wc = wave & 1;
  floatx4 acc[4][4] = {};
  const unsigned short* Vb = Vt  + (long)bh*128*N_ + c*CH_;
  const unsigned short* Kb = Ktd + (long)bh*128*N_ + c*CH_;

  #pragma unroll
  for(int kk=0;kk<4;++kk){
    int tl = kk*32 + ((lane>>4)<<3);
    short8 af[4], bfr[4];
    #pragma unroll
    for(int i=0;i<4;++i){ int dv = (wr<<6)+(i<<4)+(lane&15); af[i]  = *(const short8*)(Vb + (long)dv*N_ + tl); }
    #pragma unroll
    for(int j=0;j<4;++j){ int dk = (wc<<6)+(j<<4)+(lane&15); bfr[j] = *(const short8*)(Kb + (long)dk*N_ + tl); }
    #pragma unroll
    for(int i=0;i<4;++i)
      #pragma unroll
      for(int j=0;j<4;++j)
        acc[i][j] = __builtin_amdgcn_mfma_f32_16x16x32_bf16(af[i], bfr[j], acc[i][j], 0,0,0);
  }
  float dec = 1.f - exp2f(-5.f - (float)h);
  float scale = exp2f(127.f * log2f(dec));    // dec^{C-1}
  float* Mo = MS + ((long)bh*NC_ + c) * 16384;
  #pragma unroll
  for(int i=0;i<4;++i)
    #pragma unroll
    for(int j=0;j<4;++j)
      #pragma unroll
      for(int r=0;r<4;++r){
        int dv = (wr<<6)+(i<<4)+((lane>>4)<<2)+r;
        int dk = (wc<<6)+(j<<4)+(lane&15);
        Mo[dv*128 + dk] = acc[i][j][r] * scale;
      }
}

// ---------------- parallel scan over chunks (elementwise over state entries) ----------------
// grid = 512: [bh][p], each thread owns 4 consecutive state elements across all 16 chunks.
__global__ __launch_bounds__(256)
void k_scan(const float* __restrict__ MS, unsigned short* __restrict__ Scb,
            float* __restrict__ stateOut){
  int bid = blockIdx.x;
  int bh = bid >> 4, p = bid & 15;
  int tid = threadIdx.x, h = bh & 15;
  float dec = 1.f - exp2f(-5.f - (float)h);
  float decC = exp2f(128.f * log2f(dec));     // dec^C
  int e0 = p*1024 + tid*4;
  floatx4 S = {0.f, 0.f, 0.f, 0.f};
  const float* base = MS + (long)bh * NC_ * 16384 + e0;
  unsigned short* sb = Scb + (long)bh * NC_ * 16384 + e0;
  for(int c=0;c<NC_;++c){
    floatx4 m = *(const floatx4*)(base + (long)c*16384);
    short4v q;
    #pragma unroll
    for(int u=0;u<4;++u) q[u] = (short)f2bf(S[u]);
    *(short4v*)(sb + (long)c*16384) = q;
    S = decC * S + m;
  }
  // final state: element e = dv*128+dk (transposed layout) -> out [b][h][dk][dv]
  int dv = e0 >> 7, dk = e0 & 127;
  float* so = stateOut + (long)bh*16384 + dv;
  #pragma unroll
  for(int u=0;u<4;++u) so[(long)(dk+u)*128] = S[u];
}

// ---------------- retention output: masked decayed QK^T @ V + cross, group-norm, gate ----------------
__global__ __launch_bounds__(256)
void k_ret(const unsigned short* __restrict__ Y, const unsigned short* __restrict__ Vt,
           const unsigned short* __restrict__ Scb, unsigned short* __restrict__ RG){
  __shared__ unsigned short sQ[128*128];   // Qd = q * dec^t   (swizzled)
  __shared__ unsigned short sK[128*128];   // Kd = k * dec^-s ; reused for P
  int bid = blockIdx.x;
  int bh = bid >> 4, c = bid & 15, b = bh >> 4, h = bh & 15;
  int tid = threadIdx.x, w = tid >> 6, lane = tid & 63;
  float dec = 1.f - exp2f(-5.f - (float)h);
  float l2d = log2f(dec);

  #pragma unroll
  for(int p=0;p<8;++p){
    int t = p*16 + (tid>>4);
    long row = (long)(b*N_ + c*CH_ + t) * NCAT_ + h*128 + (tid&15)*8;
    short8 qv = *(const short8*)(Y + row);          // q section
    short8 kv = *(const short8*)(Y + row + 2048);   // k section
    float fq = exp2f((float)t * l2d);
    float fk = exp2f(-(float)t * l2d);
    short8 qs, ks;
    #pragma unroll
    for(int u=0;u<8;++u){
      qs[u] = (short)f2bf(bf2f((unsigned short)qv[u]) * fq);
      ks[u] = (short)f2bf(bf2f((unsigned short)kv[u]) * fk);
    }
    int ad = t*256 + (((tid&15)*16) ^ ((t&7)<<4));
    *(short8*)((char*)sQ + ad) = qs;
    *(short8*)((char*)sK + ad) = ks;
  }
  __syncthreads();

  floatx4 acc[2][8] = {};
  // QK^T (already includes dec^{t-s})
  #pragma unroll
  for(int kk=0;kk<4;++kk){
    int cb = (kk<<6) + ((lane>>4)<<4);
    short8 af[2], bfr[8];
    #pragma unroll
    for(int i=0;i<2;++i){ int t = w*32 + (i<<4) + (lane&15); af[i] = *(const short8*)((const char*)sQ + t*256 + (cb ^ ((t&7)<<4))); }
    #pragma unroll
    for(int j=0;j<8;++j){ int s = (j<<4) + (lane&15); bfr[j] = *(const short8*)((const char*)sK + s*256 + (cb ^ ((s&7)<<4))); }
    #pragma unroll
    for(int i=0;i<2;++i)
      #pragma unroll
      for(int j=0;j<8;++j)
        acc[i][j] = __builtin_amdgcn_mfma_f32_16x16x32_bf16(af[i], bfr[j], acc[i][j], 0,0,0);
  }
  __syncthreads();   // all waves done reading sK

  // causal mask, write P (bf16) into sK
  #pragma unroll
  for(int i=0;i<2;++i)
    #pragma unroll
    for(int j=0;j<8;++j)
      #pragma unroll
      for(int r=0;r<4;++r){
        int t = w*32 + (i<<4) + ((lane>>4)<<2) + r;
        int s = (j<<4) + (lane&15);
        float v = (s <= t) ? acc[i][j][r] : 0.f;
        *(unsigned short*)((char*)sK + t*256 + ((s*2) ^ ((t&7)<<4))) = f2bf(v);
      }
  __syncthreads();

  #pragma unroll
  for(int i=0;i<2;++i)
    #pragma unroll
    for(int j=0;j<8;++j)
      #pragma unroll
      for(int u=0;u<4;++u) acc[i][j][u] = 0.f;

  // ret = P @ V
  const unsigned short* Vb = Vt + (long)bh*128*N_ + c*CH_;
  #pragma unroll
  for(int kk=0;kk<4;++kk){
    int cb = (kk<<6) + ((lane>>4)<<4);
    int sg = kk*32 + ((lane>>4)<<3);
    short8 af[2], bfr[8];
    #pragma unroll
    for(int i=0;i<2;++i){ int t = w*32 + (i<<4) + (lane&15); af[i] = *(const short8*)((const char*)sK + t*256 + (cb ^ ((t&7)<<4))); }
    #pragma unroll
    for(int j=0;j<8;++j){ int dv = (j<<4) + (lane&15); bfr[j] = *(const short8*)(Vb + (long)dv*N_ + sg); }
    #pragma unroll
    for(int i=0;i<2;++i)
      #pragma unroll
      for(int j=0;j<8;++j)
        acc[i][j] = __builtin_amdgcn_mfma_f32_16x16x32_bf16(af[i], bfr[j], acc[i][j], 0,0,0);
  }
  // + dec^{t+1} * q @ S_c   (A = Qd*dec, B = Scb[dv][dk])
  const unsigned short* Sb = Scb + ((long)bh*NC_ + c) * 16384;
  #pragma unroll
  for(int kk=0;kk<4;++kk){
    int cb = (kk<<6) + ((lane>>4)<<4);
    int kg = kk*32 + ((lane>>4)<<3);
    short8 af[2], bfr[8];
    #pragma unroll
    for(int i=0;i<2;++i){
      int t = w*32 + (i<<4) + (lane&15);
      short8 qv = *(const short8*)((const char*)sQ + t*256 + (cb ^ ((t&7)<<4)));
      #pragma unroll
      for(int u=0;u<8;++u) af[i][u] = (short)f2bf(bf2f((unsigned short)qv[u]) * dec);
    }
    #pragma unroll
    for(int j=0;j<8;++j){ int dv = (j<<4) + (lane&15); bfr[j] = *(const short8*)(Sb + (long)dv*128 + kg); }
    #pragma unroll
    for(int i=0;i<2;++i)
      #pragma unroll
      for(int j=0;j<8;++j)
        acc[i][j] = __builtin_amdgcn_mfma_f32_16x16x32_bf16(af[i], bfr[j], acc[i][j], 0,0,0);
  }

  // group-norm over DV per row, gate, write bf16
  #pragma unroll
  for(int i=0;i<2;++i){
    #pragma unroll
    for(int r=0;r<4;++r){
      float s1 = 0.f, s2 = 0.f;
      #pragma unroll
      for(int j=0;j<8;++j){ float v = acc[i][j][r]; s1 += v; s2 += v*v; }
      #pragma unroll
      for(int off=1; off<16; off<<=1){ s1 += __shfl_xor(s1, off); s2 += __shfl_xor(s2, off); }
      float mu  = s1 * (1.f/128.f);
      float var = s2 * (1.f/128.f) - mu*mu;
      float inv = rsqrtf(var + 1e-6f);
      int t = w*32 + (i<<4) + ((lane>>4)<<2) + r;
      long mrow = (long)(b*N_ + c*CH_ + t);
      #pragma unroll
      for(int j=0;j<8;++j){
        int dv = (j<<4) + (lane&15);
        float v = (acc[i][j][r] - mu) * inv;
        float g = bf2f(Y[mrow*NCAT_ + 6144 + h*128 + dv]);
        RG[mrow*E_ + h*128 + dv] = f2bf(v * g);
      }
    }
  }
}

// ---------------- launch ----------------
extern "C" void kernel_launch(void* const* d_in, const int* in_sizes, int n_in,
                              void* d_out, int out_size, void* d_ws, size_t ws_size,
                              hipStream_t stream) {
  const float* x  = (const float*)d_in[0];
  const float* Wq = (const float*)d_in[1];
  const float* bq = (const float*)d_in[2];
  const float* Wk = (const float*)d_in[3];
  const float* bk = (const float*)d_in[4];
  const float* Wv = (const float*)d_in[5];
  const float* bv = (const float*)d_in[6];
  const float* Wg = (const float*)d_in[7];
  const float* bg = (const float*)d_in[8];
  const float* Wo = (const float*)d_in[9];
  const float* bo = (const float*)d_in[10];

  char* ws = (char*)d_ws;
  unsigned short* xb   = (unsigned short*)(ws + OFF_XB);
  unsigned short* Wcat = (unsigned short*)(ws + OFF_WCAT);
  unsigned short* Wob  = (unsigned short*)(ws + OFF_WOB);
  float*          bcat = (float*)(ws + OFF_BCAT);
  unsigned short* Y    = (unsigned short*)(ws + OFF_Y);
  unsigned short* Ktd  = (unsigned short*)(ws + OFF_KT);
  unsigned short* Vt   = (unsigned short*)(ws + OFF_VT);
  unsigned short* Scb  = (unsigned short*)(ws + OFF_SCB);
  float*          MS   = (float*)(ws + OFF_WCAT);   // reuse after GEMM1
  unsigned short* RG   = (unsigned short*)(ws + OFF_XB); // reuse after GEMM1

  float* outp     = (float*)d_out;
  float* stateOut = outp + (long)M_ * E_;   // 8,388,608

  // allow 128KB dynamic LDS for the 256^2 GEMM
  (void)hipFuncSetAttribute((const void*)k_gemm256,
                            hipFuncAttributeMaxDynamicSharedMemorySize, 131072);

  // prep
  k_cast<<<4096, 256, 0, stream>>>(x, xb, M_*E_);
  k_cast<<<2048, 256, 0, stream>>>(Wq, Wcat + 0L,        E_*E_);
  k_cast<<<2048, 256, 0, stream>>>(Wk, Wcat + 1L*E_*E_,  E_*E_);
  k_cast<<<2048, 256, 0, stream>>>(Wv, Wcat + 2L*E_*E_,  E_*E_);
  k_cast<<<2048, 256, 0, stream>>>(Wg, Wcat + 3L*E_*E_,  E_*E_);
  k_cast<<<2048, 256, 0, stream>>>(Wo, Wob, E_*E_);
  k_bcat<<<32, 256, 0, stream>>>(bq, bk, bv, bg, bcat);

  // fused QKVG projection (256^2 8-phase)
  k_gemm256<<<512, 512, 131072, stream>>>(xb, Wcat, Y, bcat);

  // t-contiguous K (decay-weighted) and V
  k_transpose<<<1024, 256, 0, stream>>>(Y, Ktd, Vt);

  // retention
  k_chunksum<<<512, 256, 0, stream>>>(Ktd, Vt, MS);
  k_scan<<<512, 256, 0, stream>>>(MS, Scb, stateOut);
  k_ret<<<512, 256, 0, stream>>>(Y, Vt, Scb, RG);

  // output projection
  k_gemm<1><<<(M_/128)*(E_/128), 256, 0, stream>>>(RG, Wob, (void*)outp, bo, M_, E_, E_, E_/128);
}

// Round 3
// 295.253 us; speedup vs baseline: 1.1501x; 1.0173x over previous
//
#include <hip/hip_runtime.h>
#include <hip/hip_bf16.h>

typedef __attribute__((ext_vector_type(8))) short short8;
typedef __attribute__((ext_vector_type(4))) short short4v;
typedef __attribute__((ext_vector_type(4))) float floatx4;

#define DI __device__ __forceinline__

// Problem constants
constexpr int B_ = 2, N_ = 2048, H_ = 16, DK_ = 128, DV_ = 128, E_ = 2048;
constexpr int M_ = B_ * N_;          // 4096 token rows
constexpr int NCAT_ = 4 * E_;        // 8192 = q|k|v|g concat
constexpr int CH_ = 128;             // chunk length
constexpr int NC_ = N_ / CH_;        // 16 chunks
constexpr float KSCALE = 0.08838834764831845f; // 1/sqrt(128)

// Workspace layout (bytes)
constexpr long OFF_XB   = 0;                    // 16MB  bf16 x      (reused as RG after GEMM1)
constexpr long OFF_WCAT = 16777216;             // 32MB  bf16 Wq|Wk|Wv|Wg  (reused as MS f32 after GEMM1)
constexpr long OFF_WOB  = 50331648;             // 8MB   bf16 Wo
constexpr long OFF_BCAT = 58720256;             // 32KB  f32 concat bias
constexpr long OFF_Y    = 58753024;             // 64MB  bf16 [4096][8192] q|k|v|silu(g)
constexpr long OFF_KT   = 125861888;            // 16MB  bf16 Ktd [b][h][dk][t]  (k * dec^-(t%128))
constexpr long OFF_VT   = 142639104;            // 16MB  bf16 Vt  [b][h][dv][t]
constexpr long OFF_SCB  = 159416320;            // 16MB  bf16 per-chunk start states [bh][c][dv][dk]

DI unsigned short f2bf(float f){
  unsigned u = __float_as_uint(f);
  u += 0x7fffu + ((u >> 16) & 1u);
  return (unsigned short)(u >> 16);
}
DI float bf2f(unsigned short s){ return __uint_as_float(((unsigned)s) << 16); }

DI void gload_lds16(const void* g, void* l){
  __builtin_amdgcn_global_load_lds(
      (const __attribute__((address_space(1))) unsigned int*)g,
      (__attribute__((address_space(3))) unsigned int*)l, 16, 0, 0);
}

// ---------------- prep: f32 -> bf16 cast ----------------
__global__ void k_cast(const float* __restrict__ s, unsigned short* __restrict__ d, int n){
  long i = ((long)blockIdx.x * blockDim.x + threadIdx.x) * 8;
  if(i >= n) return;
  float4 v0 = *(const float4*)(s + i);
  float4 v1 = *(const float4*)(s + i + 4);
  short8 o;
  o[0]=(short)f2bf(v0.x); o[1]=(short)f2bf(v0.y); o[2]=(short)f2bf(v0.z); o[3]=(short)f2bf(v0.w);
  o[4]=(short)f2bf(v1.x); o[5]=(short)f2bf(v1.y); o[6]=(short)f2bf(v1.z); o[7]=(short)f2bf(v1.w);
  *(short8*)(d + i) = o;
}

__global__ void k_bcat(const float* __restrict__ bq, const float* __restrict__ bk,
                       const float* __restrict__ bv, const float* __restrict__ bg,
                       float* __restrict__ bcat){
  int i = blockIdx.x * blockDim.x + threadIdx.x;
  float v;
  if(i < 2048)      v = bq[i];
  else if(i < 4096) v = bk[i - 2048];
  else if(i < 6144) v = bv[i - 4096];
  else              v = bg[i - 6144];
  bcat[i] = v;
}

// ================= 256x256 quadrant-phase GEMM (QKVG projection) =================
// 512 threads = 8 waves. Per phase ALL waves compute one 128x128 block-quadrant
// (order (0,0),(0,1),(1,1),(1,0)), so each phase reads exactly one A-half and one
// B-half of the current K-tile. Staging: one half-tile per phase (2 gload/wave),
// order [A0,B0,B1,A1], counted vmcnt(4) waits (never drain to 0 in the loop).
// LDS 128KB: A halves at buf*32768+half*16384, B at +65536. XOR 16B-chunk swizzle.
__global__ __launch_bounds__(512, 2)
void k_gemm256(const unsigned short* __restrict__ A,
               const unsigned short* __restrict__ Bt,
               unsigned short* __restrict__ Y,
               const float* __restrict__ bias)
{
  extern __shared__ unsigned short lds[];
  constexpr int K = 2048;
  constexpr int NKT = K / 64;

  const int tid = threadIdx.x;
  const int wave = tid >> 6, lane = tid & 63;
  const int wr = wave >> 2, wc = wave & 3;
  const int l15 = lane & 15;

  // XCD-bijective 8x8 supertile swizzle
  int bid = blockIdx.x;
  int g = bid & 7, w = bid >> 3;
  int bm = (g & 1) * 8 + (w & 7);           // 0..15
  int bn = (g >> 1) * 8 + (w >> 3);         // 0..31

  const unsigned short* Ab = A  + (long)bm * 256 * K;
  const unsigned short* Bb = Bt + (long)bn * 256 * K;

  // staging geometry: per wave, rows srow (+64 for s=1) of a 128-row half
  const int srow = wave * 8 + (lane >> 3);                    // 0..63
  const int ce   = ((lane & 7) ^ ((lane >> 3) & 7)) * 8;      // pre-swizzled source col (elems)

  // read geometry: byte col within row for kstep k: ((k*4 + lane>>4) ^ (lane&7)) * 16
  const int colb[2] = { (((lane >> 4)    ) ^ (lane & 7)) << 4,
                        (((lane >> 4) + 4 ^ (lane & 7))) << 4 };
  int rbA[4], rbB[2];
  #pragma unroll
  for(int i=0;i<4;++i) rbA[i] = (wr*64 + i*16 + l15) << 7;    // byte row base in half
  #pragma unroll
  for(int j=0;j<2;++j) rbB[j] = (wc*32 + j*16 + l15) << 7;

  floatx4 acc[4][4][2] = {};    // [quadrant][i][j]
  short8 ar[4][2], br[2][2];
  const char* ldsc = (const char*)lds;

  // stage one half: op 0 = A, 1 = B ; 2 gloads (s=0,1)
#define STG(op, buf, half, kt) do{                                                   \
    const unsigned short* _s = ((op) ? Bb : Ab) + (long)((half)*128 + srow)*K + (long)(kt)*64 + ce; \
    unsigned short* _d = lds + ((op)*32768 + (buf)*16384 + (half)*8192 + wave*512);  \
    gload_lds16(_s, _d);                                                             \
    gload_lds16(_s + 64*K, _d + 4096);                                               \
  }while(0)

#define RD_A(buf, half) do{                                                          \
    const char* _h = ldsc + (buf)*32768 + (half)*16384;                              \
    _Pragma("unroll")                                                                \
    for(int i=0;i<4;++i){ ar[i][0] = *(const short8*)(_h + rbA[i] + colb[0]);        \
                          ar[i][1] = *(const short8*)(_h + rbA[i] + colb[1]); }      \
  }while(0)

#define RD_B(buf, half) do{                                                          \
    const char* _h = ldsc + 65536 + (buf)*32768 + (half)*16384;                      \
    _Pragma("unroll")                                                                \
    for(int j=0;j<2;++j){ br[j][0] = *(const short8*)(_h + rbB[j] + colb[0]);        \
                          br[j][1] = *(const short8*)(_h + rbB[j] + colb[1]); }      \
  }while(0)

#define MFMA16(q) do{                                                                \
    __builtin_amdgcn_s_setprio(1);                                                   \
    _Pragma("unroll")                                                                \
    for(int i=0;i<4;++i)                                                             \
      _Pragma("unroll")                                                              \
      for(int j=0;j<2;++j)                                                           \
        _Pragma("unroll")                                                            \
        for(int k=0;k<2;++k)                                                         \
          acc[q][i][j] = __builtin_amdgcn_mfma_f32_16x16x32_bf16(ar[i][k], br[j][k], acc[q][i][j], 0,0,0); \
    __builtin_amdgcn_s_setprio(0);                                                   \
  }while(0)

  // prologue: stage all 4 halves of tile 0 into buf 0
  STG(0, 0, 0, 0);
  STG(1, 0, 0, 0);
  STG(1, 0, 1, 0);
  STG(0, 0, 1, 0);
  asm volatile("s_waitcnt vmcnt(0)" ::: "memory");
  __builtin_amdgcn_s_barrier();
  __builtin_amdgcn_sched_barrier(0);

  for(int u=0; u<NKT; ++u){
    const int cur = u & 1, nxt = cur ^ 1;
    const int ktn = (u + 1) & (NKT - 1);

    // ---- P0: quadrant (0,0) ----
    RD_A(cur, 0);
    RD_B(cur, 0);
    STG(0, nxt, 0, ktn);                       // A half0 of next tile
    asm volatile("s_waitcnt vmcnt(4)" ::: "memory");   // B1(cur) landed for P1
    __builtin_amdgcn_s_barrier();
    MFMA16(0);
    __builtin_amdgcn_s_barrier();
    __builtin_amdgcn_sched_barrier(0);

    // ---- P1: quadrant (0,1) ----
    RD_B(cur, 1);
    STG(1, nxt, 0, ktn);                       // B half0 of next tile
    asm volatile("s_waitcnt vmcnt(4)" ::: "memory");   // A1(cur) landed for P2
    __builtin_amdgcn_s_barrier();
    MFMA16(1);
    __builtin_amdgcn_s_barrier();
    __builtin_amdgcn_sched_barrier(0);

    // ---- P2: quadrant (1,1) ----
    RD_A(cur, 1);
    STG(1, nxt, 1, ktn);                       // B half1 of next tile
    __builtin_amdgcn_s_barrier();
    MFMA16(2);
    __builtin_amdgcn_s_barrier();
    __builtin_amdgcn_sched_barrier(0);

    // ---- P3: quadrant (1,0) ----
    RD_B(cur, 0);
    STG(0, nxt, 1, ktn);                       // A half1 of next tile
    asm volatile("s_waitcnt vmcnt(4)" ::: "memory");   // A0,B0(next) landed for next P0
    __builtin_amdgcn_s_barrier();
    MFMA16(3);
    __builtin_amdgcn_s_barrier();
    __builtin_amdgcn_sched_barrier(0);
  }
#undef STG
#undef RD_A
#undef RD_B
#undef MFMA16

  // epilogue: bias + section transforms, bf16 store
  static constexpr int QM[4] = {0,0,1,1}, QN[4] = {0,1,1,0};
  #pragma unroll
  for(int q=0;q<4;++q){
    #pragma unroll
    for(int i=0;i<4;++i){
      const int rowi = bm*256 + QM[q]*128 + wr*64 + i*16 + ((lane>>4)<<2);
      #pragma unroll
      for(int j=0;j<2;++j){
        const int col = bn*256 + QN[q]*128 + wc*32 + j*16 + l15;
        const float bs = bias[col];
        const int sec = col >> 11;
        #pragma unroll
        for(int r=0;r<4;++r){
          float v = acc[q][i][j][r] + bs;
          if(sec == 1) v *= KSCALE;
          else if(sec == 3) v = v / (1.f + __expf(-v));   // silu
          Y[(long)(rowi + r) * NCAT_ + col] = f2bf(v);
        }
      }
    }
  }
}

// ---------------- 128^2 GEMM (kept for output projection) ----------------
template<int EPI>
__global__ __launch_bounds__(256)
void k_gemm(const unsigned short* __restrict__ A,
            const unsigned short* __restrict__ Bt,
            void* __restrict__ outp,
            const float* __restrict__ bias,
            int M, int Ncols, int K, int NB)
{
  __shared__ unsigned short lA[128*64];
  __shared__ unsigned short lB[128*64];
  const int bid = blockIdx.x;
  const int bm = bid / NB, bn = bid % NB;
  const int tid = threadIdx.x;
  const int wave = tid >> 6, lane = tid & 63;
  const int wr = wave >> 1, wc = wave & 1;

  floatx4 acc[4][4] = {};

  int srow[4], scol[4];
  #pragma unroll
  for(int is=0; is<4; ++is){
    int o = is*4096 + wave*1024 + lane*16;     // byte offset in 16KB tile
    int row = o >> 7;
    int logcb = (o & 127) ^ ((row & 7) << 4);  // inverse-swizzled source column
    srow[is] = row; scol[is] = logcb >> 1;
  }
  const unsigned short* Abase = A + (long)bm * 128 * K;
  const unsigned short* Bbase = Bt + (long)bn * 128 * K;

  const int nkt = K >> 6;
  for(int kt=0; kt<nkt; ++kt){
    const int k0 = kt << 6;
    #pragma unroll
    for(int is=0; is<4; ++is){
      gload_lds16(Abase + (long)srow[is]*K + k0 + scol[is], &lA[(is*4096 + wave*1024) >> 1]);
      gload_lds16(Bbase + (long)srow[is]*K + k0 + scol[is], &lB[(is*4096 + wave*1024) >> 1]);
    }
    __syncthreads();
    #pragma unroll
    for(int kk=0; kk<2; ++kk){
      const int cb = (kk<<6) + ((lane>>4)<<4);
      short8 af[4], bfr[4];
      #pragma unroll
      for(int i=0;i<4;++i){
        int row = (wr<<6) + (i<<4) + (lane&15);
        af[i] = *(const short8*)((const char*)lA + (row<<7) + (cb ^ ((row&7)<<4)));
      }
      #pragma unroll
      for(int j=0;j<4;++j){
        int row = (wc<<6) + (j<<4) + (lane&15);
        bfr[j] = *(const short8*)((const char*)lB + (row<<7) + (cb ^ ((row&7)<<4)));
      }
      #pragma unroll
      for(int i=0;i<4;++i)
        #pragma unroll
        for(int j=0;j<4;++j)
          acc[i][j] = __builtin_amdgcn_mfma_f32_16x16x32_bf16(af[i], bfr[j], acc[i][j], 0,0,0);
    }
    __syncthreads();
  }

  #pragma unroll
  for(int i=0;i<4;++i){
    #pragma unroll
    for(int j=0;j<4;++j){
      #pragma unroll
      for(int r=0;r<4;++r){
        int row = bm*128 + (wr<<6) + (i<<4) + ((lane>>4)<<2) + r;
        int col = bn*128 + (wc<<6) + (j<<4) + (lane&15);
        float v = acc[i][j][r] + bias[col];
        if(EPI == 0){
          int sec = col >> 11;
          if(sec == 1) v *= KSCALE;
          else if(sec == 3) v = v / (1.f + __expf(-v));   // silu
          ((unsigned short*)outp)[(long)row * Ncols + col] = f2bf(v);
        } else {
          ((float*)outp)[(long)row * Ncols + col] = v;
        }
      }
    }
  }
}

// ---------------- transpose K,V to t-contiguous; bake dec^-(t%128) into K ----------------
__global__ __launch_bounds__(256)
void k_transpose(const unsigned short* __restrict__ Y,
                 unsigned short* __restrict__ Kt, unsigned short* __restrict__ Vt){
  __shared__ unsigned short lt[128][136];
  int bid = blockIdx.x;
  int op = bid >> 9;            // 0: K, 1: V
  int r  = bid & 511;
  int bh = r >> 4, c = r & 15, b = bh >> 4, h = bh & 15;
  int tid = threadIdx.x;
  float dec = 1.f - exp2f(-5.f - (float)h);
  float l2d = log2f(dec);
  int sec = op ? 4096 : 2048;
  unsigned short* Dst = op ? Vt : Kt;

  #pragma unroll
  for(int p=0;p<8;++p){
    int t = p*16 + (tid>>4);
    long src = ((long)(b*N_ + c*CH_ + t)) * NCAT_ + sec + h*128 + (tid&15)*8;
    short8 v = *(const short8*)(Y + src);
    if(op == 0){
      float f = exp2f(-(float)t * l2d);   // dec^{-t}
      #pragma unroll
      for(int u=0;u<8;++u) v[u] = (short)f2bf(bf2f((unsigned short)v[u]) * f);
    }
    *(short8*)&lt[t][(tid&15)*8] = v;
  }
  __syncthreads();
  #pragma unroll
  for(int p=0;p<8;++p){
    int dk = p*16 + (tid>>4);
    int tc = (tid&15)*8;
    short8 o;
    #pragma unroll
    for(int u=0;u<8;++u) o[u] = (short)lt[tc+u][dk];
    *(short8*)(Dst + ((long)(bh*128 + dk)) * N_ + c*CH_ + tc) = o;
  }
}

// ---------------- per-chunk summary Mt_c[dv][dk] = dec^{C-1} * sum_t Vt[dv][t]*Ktd[dk][t] ----------------
__global__ __launch_bounds__(256)
void k_chunksum(const unsigned short* __restrict__ Ktd, const unsigned short* __restrict__ Vt,
                float* __restrict__ MS){
  int bid = blockIdx.x;            // 512: bh*16 + c
  int bh = bid >> 4, c = bid & 15, h = bh & 15;
  int tid = threadIdx.x, wave = tid >> 6, lane = tid & 63;
  int wr = wave >> 1, wc = wave & 1;
  floatx4 acc[4][4] = {};
  const unsigned short* Vb = Vt  + (long)bh*128*N_ + c*CH_;
  const unsigned short* Kb = Ktd + (long)bh*128*N_ + c*CH_;

  #pragma unroll
  for(int kk=0;kk<4;++kk){
    int tl = kk*32 + ((lane>>4)<<3);
    short8 af[4], bfr[4];
    #pragma unroll
    for(int i=0;i<4;++i){ int dv = (wr<<6)+(i<<4)+(lane&15); af[i]  = *(const short8*)(Vb + (long)dv*N_ + tl); }
    #pragma unroll
    for(int j=0;j<4;++j){ int dk = (wc<<6)+(j<<4)+(lane&15); bfr[j] = *(const short8*)(Kb + (long)dk*N_ + tl); }
    #pragma unroll
    for(int i=0;i<4;++i)
      #pragma unroll
      for(int j=0;j<4;++j)
        acc[i][j] = __builtin_amdgcn_mfma_f32_16x16x32_bf16(af[i], bfr[j], acc[i][j], 0,0,0);
  }
  float dec = 1.f - exp2f(-5.f - (float)h);
  float scale = exp2f(127.f * log2f(dec));    // dec^{C-1}
  float* Mo = MS + ((long)bh*NC_ + c) * 16384;
  #pragma unroll
  for(int i=0;i<4;++i)
    #pragma unroll
    for(int j=0;j<4;++j)
      #pragma unroll
      for(int r=0;r<4;++r){
        int dv = (wr<<6)+(i<<4)+((lane>>4)<<2)+r;
        int dk = (wc<<6)+(j<<4)+(lane&15);
        Mo[dv*128 + dk] = acc[i][j][r] * scale;
      }
}

// ---------------- parallel scan over chunks (elementwise over state entries) ----------------
__global__ __launch_bounds__(256)
void k_scan(const float* __restrict__ MS, unsigned short* __restrict__ Scb,
            float* __restrict__ stateOut){
  int bid = blockIdx.x;
  int bh = bid >> 4, p = bid & 15;
  int tid = threadIdx.x, h = bh & 15;
  float dec = 1.f - exp2f(-5.f - (float)h);
  float decC = exp2f(128.f * log2f(dec));     // dec^C
  int e0 = p*1024 + tid*4;
  floatx4 S = {0.f, 0.f, 0.f, 0.f};
  const float* base = MS + (long)bh * NC_ * 16384 + e0;
  unsigned short* sb = Scb + (long)bh * NC_ * 16384 + e0;
  for(int c=0;c<NC_;++c){
    floatx4 m = *(const floatx4*)(base + (long)c*16384);
    short4v q;
    #pragma unroll
    for(int u=0;u<4;++u) q[u] = (short)f2bf(S[u]);
    *(short4v*)(sb + (long)c*16384) = q;
    S = decC * S + m;
  }
  // final state: element e = dv*128+dk (transposed layout) -> out [b][h][dk][dv]
  int dv = e0 >> 7, dk = e0 & 127;
  float* so = stateOut + (long)bh*16384 + dv;
  #pragma unroll
  for(int u=0;u<4;++u) so[(long)(dk+u)*128] = S[u];
}

// ---------------- retention output: masked decayed QK^T @ V + cross, group-norm, gate ----------------
__global__ __launch_bounds__(256)
void k_ret(const unsigned short* __restrict__ Y, const unsigned short* __restrict__ Vt,
           const unsigned short* __restrict__ Scb, unsigned short* __restrict__ RG){
  __shared__ unsigned short sQ[128*128];   // Qd = q * dec^t   (swizzled)
  __shared__ unsigned short sK[128*128];   // Kd = k * dec^-s ; reused for P
  int bid = blockIdx.x;
  int bh = bid >> 4, c = bid & 15, b = bh >> 4, h = bh & 15;
  int tid = threadIdx.x, w = tid >> 6, lane = tid & 63;
  float dec = 1.f - exp2f(-5.f - (float)h);
  float l2d = log2f(dec);

  #pragma unroll
  for(int p=0;p<8;++p){
    int t = p*16 + (tid>>4);
    long row = (long)(b*N_ + c*CH_ + t) * NCAT_ + h*128 + (tid&15)*8;
    short8 qv = *(const short8*)(Y + row);          // q section
    short8 kv = *(const short8*)(Y + row + 2048);   // k section
    float fq = exp2f((float)t * l2d);
    float fk = exp2f(-(float)t * l2d);
    short8 qs, ks;
    #pragma unroll
    for(int u=0;u<8;++u){
      qs[u] = (short)f2bf(bf2f((unsigned short)qv[u]) * fq);
      ks[u] = (short)f2bf(bf2f((unsigned short)kv[u]) * fk);
    }
    int ad = t*256 + (((tid&15)*16) ^ ((t&7)<<4));
    *(short8*)((char*)sQ + ad) = qs;
    *(short8*)((char*)sK + ad) = ks;
  }
  __syncthreads();

  floatx4 acc[2][8] = {};
  // QK^T (already includes dec^{t-s})
  #pragma unroll
  for(int kk=0;kk<4;++kk){
    int cb = (kk<<6) + ((lane>>4)<<4);
    short8 af[2], bfr[8];
    #pragma unroll
    for(int i=0;i<2;++i){ int t = w*32 + (i<<4) + (lane&15); af[i] = *(const short8*)((const char*)sQ + t*256 + (cb ^ ((t&7)<<4))); }
    #pragma unroll
    for(int j=0;j<8;++j){ int s = (j<<4) + (lane&15); bfr[j] = *(const short8*)((const char*)sK + s*256 + (cb ^ ((s&7)<<4))); }
    #pragma unroll
    for(int i=0;i<2;++i)
      #pragma unroll
      for(int j=0;j<8;++j)
        acc[i][j] = __builtin_amdgcn_mfma_f32_16x16x32_bf16(af[i], bfr[j], acc[i][j], 0,0,0);
  }
  __syncthreads();   // all waves done reading sK

  // causal mask, write P (bf16) into sK
  #pragma unroll
  for(int i=0;i<2;++i)
    #pragma unroll
    for(int j=0;j<8;++j)
      #pragma unroll
      for(int r=0;r<4;++r){
        int t = w*32 + (i<<4) + ((lane>>4)<<2) + r;
        int s = (j<<4) + (lane&15);
        float v = (s <= t) ? acc[i][j][r] : 0.f;
        *(unsigned short*)((char*)sK + t*256 + ((s*2) ^ ((t&7)<<4))) = f2bf(v);
      }
  __syncthreads();

  #pragma unroll
  for(int i=0;i<2;++i)
    #pragma unroll
    for(int j=0;j<8;++j)
      #pragma unroll
      for(int u=0;u<4;++u) acc[i][j][u] = 0.f;

  // ret = P @ V
  const unsigned short* Vb = Vt + (long)bh*128*N_ + c*CH_;
  #pragma unroll
  for(int kk=0;kk<4;++kk){
    int cb = (kk<<6) + ((lane>>4)<<4);
    int sg = kk*32 + ((lane>>4)<<3);
    short8 af[2], bfr[8];
    #pragma unroll
    for(int i=0;i<2;++i){ int t = w*32 + (i<<4) + (lane&15); af[i] = *(const short8*)((const char*)sK + t*256 + (cb ^ ((t&7)<<4))); }
    #pragma unroll
    for(int j=0;j<8;++j){ int dv = (j<<4) + (lane&15); bfr[j] = *(const short8*)(Vb + (long)dv*N_ + sg); }
    #pragma unroll
    for(int i=0;i<2;++i)
      #pragma unroll
      for(int j=0;j<8;++j)
        acc[i][j] = __builtin_amdgcn_mfma_f32_16x16x32_bf16(af[i], bfr[j], acc[i][j], 0,0,0);
  }
  // + dec^{t+1} * q @ S_c   (A = Qd*dec, B = Scb[dv][dk])
  const unsigned short* Sb = Scb + ((long)bh*NC_ + c) * 16384;
  #pragma unroll
  for(int kk=0;kk<4;++kk){
    int cb = (kk<<6) + ((lane>>4)<<4);
    int kg = kk*32 + ((lane>>4)<<3);
    short8 af[2], bfr[8];
    #pragma unroll
    for(int i=0;i<2;++i){
      int t = w*32 + (i<<4) + (lane&15);
      short8 qv = *(const short8*)((const char*)sQ + t*256 + (cb ^ ((t&7)<<4)));
      #pragma unroll
      for(int u=0;u<8;++u) af[i][u] = (short)f2bf(bf2f((unsigned short)qv[u]) * dec);
    }
    #pragma unroll
    for(int j=0;j<8;++j){ int dv = (j<<4) + (lane&15); bfr[j] = *(const short8*)(Sb + (long)dv*128 + kg); }
    #pragma unroll
    for(int i=0;i<2;++i)
      #pragma unroll
      for(int j=0;j<8;++j)
        acc[i][j] = __builtin_amdgcn_mfma_f32_16x16x32_bf16(af[i], bfr[j], acc[i][j], 0,0,0);
  }

  // group-norm over DV per row, gate, write bf16
  #pragma unroll
  for(int i=0;i<2;++i){
    #pragma unroll
    for(int r=0;r<4;++r){
      float s1 = 0.f, s2 = 0.f;
      #pragma unroll
      for(int j=0;j<8;++j){ float v = acc[i][j][r]; s1 += v; s2 += v*v; }
      #pragma unroll
      for(int off=1; off<16; off<<=1){ s1 += __shfl_xor(s1, off); s2 += __shfl_xor(s2, off); }
      float mu  = s1 * (1.f/128.f);
      float var = s2 * (1.f/128.f) - mu*mu;
      float inv = rsqrtf(var + 1e-6f);
      int t = w*32 + (i<<4) + ((lane>>4)<<2) + r;
      long mrow = (long)(b*N_ + c*CH_ + t);
      #pragma unroll
      for(int j=0;j<8;++j){
        int dv = (j<<4) + (lane&15);
        float v = (acc[i][j][r] - mu) * inv;
        float g = bf2f(Y[mrow*NCAT_ + 6144 + h*128 + dv]);
        RG[mrow*E_ + h*128 + dv] = f2bf(v * g);
      }
    }
  }
}

// ---------------- launch ----------------
extern "C" void kernel_launch(void* const* d_in, const int* in_sizes, int n_in,
                              void* d_out, int out_size, void* d_ws, size_t ws_size,
                              hipStream_t stream) {
  const float* x  = (const float*)d_in[0];
  const float* Wq = (const float*)d_in[1];
  const float* bq = (const float*)d_in[2];
  const float* Wk = (const float*)d_in[3];
  const float* bk = (const float*)d_in[4];
  const float* Wv = (const float*)d_in[5];
  const float* bv = (const float*)d_in[6];
  const float* Wg = (const float*)d_in[7];
  const float* bg = (const float*)d_in[8];
  const float* Wo = (const float*)d_in[9];
  const float* bo = (const float*)d_in[10];

  char* ws = (char*)d_ws;
  unsigned short* xb   = (unsigned short*)(ws + OFF_XB);
  unsigned short* Wcat = (unsigned short*)(ws + OFF_WCAT);
  unsigned short* Wob  = (unsigned short*)(ws + OFF_WOB);
  float*          bcat = (float*)(ws + OFF_BCAT);
  unsigned short* Y    = (unsigned short*)(ws + OFF_Y);
  unsigned short* Ktd  = (unsigned short*)(ws + OFF_KT);
  unsigned short* Vt   = (unsigned short*)(ws + OFF_VT);
  unsigned short* Scb  = (unsigned short*)(ws + OFF_SCB);
  float*          MS   = (float*)(ws + OFF_WCAT);   // reuse after GEMM1
  unsigned short* RG   = (unsigned short*)(ws + OFF_XB); // reuse after GEMM1

  float* outp     = (float*)d_out;
  float* stateOut = outp + (long)M_ * E_;   // 8,388,608

  // allow 128KB dynamic LDS for the 256^2 GEMM
  (void)hipFuncSetAttribute((const void*)k_gemm256,
                            hipFuncAttributeMaxDynamicSharedMemorySize, 131072);

  // prep
  k_cast<<<4096, 256, 0, stream>>>(x, xb, M_*E_);
  k_cast<<<2048, 256, 0, stream>>>(Wq, Wcat + 0L,        E_*E_);
  k_cast<<<2048, 256, 0, stream>>>(Wk, Wcat + 1L*E_*E_,  E_*E_);
  k_cast<<<2048, 256, 0, stream>>>(Wv, Wcat + 2L*E_*E_,  E_*E_);
  k_cast<<<2048, 256, 0, stream>>>(Wg, Wcat + 3L*E_*E_,  E_*E_);
  k_cast<<<2048, 256, 0, stream>>>(Wo, Wob, E_*E_);
  k_bcat<<<32, 256, 0, stream>>>(bq, bk, bv, bg, bcat);

  // fused QKVG projection (256^2 quadrant-phase)
  k_gemm256<<<512, 512, 131072, stream>>>(xb, Wcat, Y, bcat);

  // t-contiguous K (decay-weighted) and V
  k_transpose<<<1024, 256, 0, stream>>>(Y, Ktd, Vt);

  // retention
  k_chunksum<<<512, 256, 0, stream>>>(Ktd, Vt, MS);
  k_scan<<<512, 256, 0, stream>>>(MS, Scb, stateOut);
  k_ret<<<512, 256, 0, stream>>>(Y, Vt, Scb, RG);

  // output projection
  k_gemm<1><<<(M_/128)*(E_/128), 256, 0, stream>>>(RG, Wob, (void*)outp, bo, M_, E_, E_, E_/128);
}